// Round 5
// baseline (62.941 us; speedup 1.0000x reference)
//
#include <hip/hip_runtime.h>
#include <math.h>

#define TPB 256

typedef unsigned long long u64;
typedef unsigned int u32;

// Packed sort key: strictly increasing in value; ties -> smaller index wins.
// u64 compare (>) == better(v1,i1,v2,i2) from jnp.argsort(-scores) stability.
__device__ __forceinline__ u64 mkkey(float v, int idx) {
    u32 u = __float_as_uint(v);
    u ^= (u32)(((int)u) >> 31) | 0x80000000u;   // monotone float->uint map
    return ((u64)u << 32) | (u32)(~idx);
}

// Branchless top-5 update on named u64 scalars (k0 >= k1 >= ... >= k4).
// Select ladder, no CFG, no private arrays (rule #20).
#define UPD(v, idx)                                             \
    {                                                           \
        const u64 _key = mkkey((v), (idx));                     \
        const bool c0 = _key > k0;                              \
        const bool c1 = _key > k1;                              \
        const bool c2 = _key > k2;                              \
        const bool c3 = _key > k3;                              \
        const bool c4 = _key > k4;                              \
        k4 = c3 ? k3 : (c4 ? _key : k4);                        \
        k3 = c2 ? k2 : (c3 ? _key : k3);                        \
        k2 = c1 ? k1 : (c2 ? _key : k2);                        \
        k1 = c0 ? k0 : (c1 ? _key : k1);                        \
        k0 = c0 ? _key : k0;                                    \
    }

// Process one quad already in registers. Fully branchless.
#define PROC(p, t, r, qi)                                                   \
    {                                                                       \
        float d;                                                            \
        d = p.x - t.x; accb = fmaf(d, d, accb);                             \
        d = p.y - t.y; accb = fmaf(d, d, accb);                             \
        d = p.z - t.z; accb = fmaf(d, d, accb);                             \
        d = p.w - t.w; accb = fmaf(d, d, accb);                             \
        accr += (r.x >= 2.0f ? r.x : 0.0f) + (r.y >= 2.0f ? r.y : 0.0f)     \
              + (r.z >= 2.0f ? r.z : 0.0f) + (r.w >= 2.0f ? r.w : 0.0f);    \
        const int _b = (qi) * 4;                                            \
        UPD(p.x, _b);                                                       \
        UPD(p.y, _b + 1);                                                   \
        UPD(p.z, _b + 2);                                                   \
        UPD(p.w, _b + 3);                                                   \
    }

// Issue all 3 loads for quad k (interleaved p,t,r so quad j is ready at
// vmcnt(24-3(j+1)) — compiler inserts the fine-grained waits).
#define LOADQ(k)                                                            \
    const int q##k = i + (k) * nthreads;                                    \
    const float4 P##k = pred4[q##k];                                        \
    const float4 T##k = tru4[q##k];                                         \
    const float4 R##k = ret4[q##k];

// min-waves-per-EU = 1: lift the occupancy-driven VGPR cap so the 24
// in-flight float4 destinations can live in registers (MLP >> TLP here).
__global__ __launch_bounds__(TPB, 1) void reward_pass1(
        const float* __restrict__ pred,
        const float* __restrict__ tru,
        const float* __restrict__ ret,
        double* __restrict__ blk_sum,
        u64* __restrict__ cand_k,
        int n) {
    const int tid = blockIdx.x * blockDim.x + threadIdx.x;
    const int nthreads = gridDim.x * blockDim.x;
    const int n4 = n >> 2;

    const float4* __restrict__ pred4 = (const float4*)pred;
    const float4* __restrict__ tru4  = (const float4*)tru;
    const float4* __restrict__ ret4  = (const float4*)ret;

    float accb = 0.0f;   // sum of (pred-true)^2
    float accr = 0.0f;   // sum of ret where ret >= 2 (rest_adj = 0.0015 * that)
    u64 k0 = 0, k1 = 0, k2 = 0, k3 = 0, k4 = 0;  // real keys are always > 0

    int i = tid;
    // Batch of 8 quads: 24 x 16B loads issued BEFORE the scheduling fence.
    // sched_barrier(0) = nothing may cross -> loads cannot be sunk to uses.
    for (; i + 7 * nthreads < n4; i += 8 * nthreads) {
        LOADQ(0) LOADQ(1) LOADQ(2) LOADQ(3)
        LOADQ(4) LOADQ(5) LOADQ(6) LOADQ(7)
        __builtin_amdgcn_sched_barrier(0);
        PROC(P0, T0, R0, q0)
        PROC(P1, T1, R1, q1)
        PROC(P2, T2, R2, q2)
        PROC(P3, T3, R3, q3)
        PROC(P4, T4, R4, q4)
        PROC(P5, T5, R5, q5)
        PROC(P6, T6, R6, q6)
        PROC(P7, T7, R7, q7)
    }
    for (; i < n4; i += nthreads) {
        const float4 p = pred4[i];
        const float4 t = tru4[i];
        const float4 r = ret4[i];
        PROC(p, t, r, i)
    }

    // Scalar tail (n not multiple of 4), handled by global thread 0.
    if (tid == 0) {
        for (int kk = n4 * 4; kk < n; ++kk) {
            float d = pred[kk] - tru[kk];
            accb = fmaf(d, d, accb);
            float rr = ret[kk];
            accr += (rr >= 2.0f ? rr : 0.0f);
            UPD(pred[kk], kk);
        }
    }

    const int lane = threadIdx.x & 63;
    const int wid  = threadIdx.x >> 6;

    // Block sum: wave shuffle reduce (double), then 4 wave partials via LDS.
    double acc = (double)accb + 0.0015 * (double)accr;
    for (int off = 32; off > 0; off >>= 1) acc += __shfl_down(acc, off);
    __shared__ double wsum[4];
    if (lane == 0) wsum[wid] = acc;
    __syncthreads();
    if (threadIdx.x == 0)
        blk_sum[blockIdx.x] = wsum[0] + wsum[1] + wsum[2] + wsum[3];

    // Block top-5: 5 rounds of (wave shfl argmax on keys -> cross-wave -> pop).
    __shared__ u64 bsk[4];
    for (int r = 0; r < 5; ++r) {
        const u64 ck = k0;
        u64 wk = ck;
        for (int off = 1; off < 64; off <<= 1) {
            u64 ok = __shfl_xor(wk, off);
            if (ok > wk) wk = ok;
        }
        if (lane == 0) bsk[wid] = wk;
        __syncthreads();
        u64 gk = bsk[0];
        if (bsk[1] > gk) gk = bsk[1];
        if (bsk[2] > gk) gk = bsk[2];
        if (bsk[3] > gk) gk = bsk[3];
        if (threadIdx.x == 0) cand_k[blockIdx.x * 5 + r] = gk;
        if (gk == ck) {  // keys unique -> exactly one owner pops
            k0 = k1; k1 = k2; k2 = k3; k3 = k4; k4 = 0;
        }
        __syncthreads();  // WAR: bsk reused next round
    }
}

__global__ __launch_bounds__(TPB) void reward_pass2(
        const double* __restrict__ blk_sum,
        const u64* __restrict__ cand_k,
        const float* __restrict__ ret,
        float* __restrict__ out,
        int nb, int n) {
    const int lane = threadIdx.x & 63;
    const int wid  = threadIdx.x >> 6;

    // Sum of partials.
    double acc = 0.0;
    for (int i = threadIdx.x; i < nb; i += TPB) acc += blk_sum[i];
    for (int off = 32; off > 0; off >>= 1) acc += __shfl_down(acc, off);
    __shared__ double wsum[4];
    if (lane == 0) wsum[wid] = acc;
    __syncthreads();

    // Per-thread top-5 over candidate keys (branchless ladder).
    u64 k0 = 0, k1 = 0, k2 = 0, k3 = 0, k4 = 0;
    const int nc = nb * 5;
    for (int i = threadIdx.x; i < nc; i += TPB) {
        const u64 _key = cand_k[i];
        const bool c0 = _key > k0;
        const bool c1 = _key > k1;
        const bool c2 = _key > k2;
        const bool c3 = _key > k3;
        const bool c4 = _key > k4;
        k4 = c3 ? k3 : (c4 ? _key : k4);
        k3 = c2 ? k2 : (c3 ? _key : k3);
        k2 = c1 ? k1 : (c2 ? _key : k2);
        k1 = c0 ? k0 : (c1 ? _key : k1);
        k0 = c0 ? _key : k0;
    }

    // 5 rounds block argmax + pop -> global top-5 indices.
    __shared__ u64 bsk[4];
    __shared__ int winner[5];
    for (int r = 0; r < 5; ++r) {
        const u64 ck = k0;
        u64 wk = ck;
        for (int off = 1; off < 64; off <<= 1) {
            u64 ok = __shfl_xor(wk, off);
            if (ok > wk) wk = ok;
        }
        if (lane == 0) bsk[wid] = wk;
        __syncthreads();
        u64 gk = bsk[0];
        if (bsk[1] > gk) gk = bsk[1];
        if (bsk[2] > gk) gk = bsk[2];
        if (bsk[3] > gk) gk = bsk[3];
        if (threadIdx.x == 0) winner[r] = (int)(~(u32)gk);
        if (gk == ck) {
            k0 = k1; k1 = k2; k2 = k3; k3 = k4; k4 = 0;
        }
        __syncthreads();
    }

    if (threadIdx.x == 0) {
        double corr = 0.0;
        for (int r = 0; r < 5; ++r) {
            int idx = winner[r];
            float rr = ret[idx];
            float a = fabsf(rr);
            float strict, mid;
            if (rr < 0.0f)       { strict = 0.005f * a;  mid = 0.0025f * a; }
            else if (rr >= 2.0f) { strict = -0.02f * rr; mid = -0.01f * rr; }
            else if (rr > 0.0f)  { strict = -0.01f * rr; mid = -0.005f * rr; }
            else                 { strict = 0.0f;        mid = 0.0f; }
            float rest = (rr >= 2.0f) ? 0.0015f * rr : 0.0f;
            float bucket = (r < 3) ? strict : mid;  // ranks 1..3 strict, 4..5 mid
            corr += (double)(bucket - rest);
        }
        out[0] = (float)((wsum[0] + wsum[1] + wsum[2] + wsum[3] + corr) / (double)n);
    }
}

extern "C" void kernel_launch(void* const* d_in, const int* in_sizes, int n_in,
                              void* d_out, int out_size, void* d_ws, size_t ws_size,
                              hipStream_t stream) {
    const float* pred = (const float*)d_in[0];
    const float* tru  = (const float*)d_in[1];
    const float* ret  = (const float*)d_in[2];
    float* out = (float*)d_out;
    const int n = in_sizes[0];

    int nb = 2048;
    // Per-block scratch: 8B sum + 5*8B candidate keys = 48B. Fit within ws_size.
    while (nb > 64 && (size_t)nb * 48 > ws_size) nb >>= 1;

    double* blk_sum = (double*)d_ws;
    u64*    cand_k  = (u64*)(blk_sum + nb);

    reward_pass1<<<nb, TPB, 0, stream>>>(pred, tru, ret, blk_sum, cand_k, n);
    reward_pass2<<<1, TPB, 0, stream>>>(blk_sum, cand_k, ret, out, nb, n);
}

// Round 6
// 58.789 us; speedup vs baseline: 1.0706x; 1.0706x over previous
//
#include <hip/hip_runtime.h>
#include <math.h>

#define TPB 256

typedef unsigned long long u64;
typedef unsigned int u32;
// Clang ext vector: __builtin_nontemporal_load needs a builtin vector type
// (HIP's float4 struct won't do). Emits global_load_dwordx4 ... nt.
typedef float f4 __attribute__((ext_vector_type(4)));

// Packed sort key: strictly increasing in value; ties -> smaller index wins.
// u64 compare (>) == better(v1,i1,v2,i2) from jnp.argsort(-scores) stability.
__device__ __forceinline__ u64 mkkey(float v, int idx) {
    u32 u = __float_as_uint(v);
    u ^= (u32)(((int)u) >> 31) | 0x80000000u;   // monotone float->uint map
    return ((u64)u << 32) | (u32)(~idx);
}

// Branchless top-5 update on named u64 scalars (k0 >= k1 >= ... >= k4).
// Select ladder, no CFG, no private arrays (rule #20).
#define UPD(v, idx)                                             \
    {                                                           \
        const u64 _key = mkkey((v), (idx));                     \
        const bool c0 = _key > k0;                              \
        const bool c1 = _key > k1;                              \
        const bool c2 = _key > k2;                              \
        const bool c3 = _key > k3;                              \
        const bool c4 = _key > k4;                              \
        k4 = c3 ? k3 : (c4 ? _key : k4);                        \
        k3 = c2 ? k2 : (c3 ? _key : k3);                        \
        k2 = c1 ? k1 : (c2 ? _key : k2);                        \
        k1 = c0 ? k0 : (c1 ? _key : k1);                        \
        k0 = c0 ? _key : k0;                                    \
    }

// Process one quad already in registers. Fully branchless.
#define PROC(p, t, r, qi)                                                   \
    {                                                                       \
        float d;                                                            \
        d = p.x - t.x; accb = fmaf(d, d, accb);                             \
        d = p.y - t.y; accb = fmaf(d, d, accb);                             \
        d = p.z - t.z; accb = fmaf(d, d, accb);                             \
        d = p.w - t.w; accb = fmaf(d, d, accb);                             \
        accr += (r.x >= 2.0f ? r.x : 0.0f) + (r.y >= 2.0f ? r.y : 0.0f)     \
              + (r.z >= 2.0f ? r.z : 0.0f) + (r.w >= 2.0f ? r.w : 0.0f);    \
        const int _b = (qi) * 4;                                            \
        UPD(p.x, _b);                                                       \
        UPD(p.y, _b + 1);                                                   \
        UPD(p.z, _b + 2);                                                   \
        UPD(p.w, _b + 3);                                                   \
    }

#define NTLOAD(ptr) __builtin_nontemporal_load(ptr)

__global__ __launch_bounds__(TPB) void reward_pass1(
        const float* __restrict__ pred,
        const float* __restrict__ tru,
        const float* __restrict__ ret,
        double* __restrict__ blk_sum,
        u64* __restrict__ cand_k,
        int n) {
    const int tid = blockIdx.x * blockDim.x + threadIdx.x;
    const int nthreads = gridDim.x * blockDim.x;
    const int n4 = n >> 2;

    const f4* __restrict__ pred4 = (const f4*)pred;
    const f4* __restrict__ tru4  = (const f4*)tru;
    const f4* __restrict__ ret4  = (const f4*)ret;

    float accb = 0.0f;   // sum of (pred-true)^2
    float accr = 0.0f;   // sum of ret where ret >= 2 (rest_adj = 0.0015 * that)
    u64 k0 = 0, k1 = 0, k2 = 0, k3 = 0, k4 = 0;  // real keys are always > 0

    // R4 structure (best-equal) + nontemporal loads (the ONE change this
    // round): bypass Infinity-Cache allocation so all traffic streams from
    // HBM at the pure-HBM service rate instead of the pathological ~50%
    // L3-hit mix (FETCH_SIZE was pinned at 98 MB of a 201 MB footprint).
    int i = tid;
    for (; i + 3 * nthreads < n4; i += 4 * nthreads) {
        const int ia = i;
        const int ib = i + nthreads;
        const int ic = i + 2 * nthreads;
        const int id = i + 3 * nthreads;
        f4 pa = NTLOAD(pred4 + ia), pb = NTLOAD(pred4 + ib),
           pc = NTLOAD(pred4 + ic), pd = NTLOAD(pred4 + id);
        f4 ta = NTLOAD(tru4 + ia),  tb = NTLOAD(tru4 + ib),
           tc = NTLOAD(tru4 + ic),  td = NTLOAD(tru4 + id);
        f4 ra = NTLOAD(ret4 + ia),  rb = NTLOAD(ret4 + ib),
           rc = NTLOAD(ret4 + ic),  rd = NTLOAD(ret4 + id);
        PROC(pa, ta, ra, ia)
        PROC(pb, tb, rb, ib)
        PROC(pc, tc, rc, ic)
        PROC(pd, td, rd, id)
    }
    for (; i < n4; i += nthreads) {
        const f4 p = NTLOAD(pred4 + i);
        const f4 t = NTLOAD(tru4 + i);
        const f4 r = NTLOAD(ret4 + i);
        PROC(p, t, r, i)
    }

    // Scalar tail (n not multiple of 4), handled by global thread 0.
    if (tid == 0) {
        for (int kk = n4 * 4; kk < n; ++kk) {
            float d = pred[kk] - tru[kk];
            accb = fmaf(d, d, accb);
            float rr = ret[kk];
            accr += (rr >= 2.0f ? rr : 0.0f);
            UPD(pred[kk], kk);
        }
    }

    const int lane = threadIdx.x & 63;
    const int wid  = threadIdx.x >> 6;

    // Block sum: wave shuffle reduce (double), then 4 wave partials via LDS.
    double acc = (double)accb + 0.0015 * (double)accr;
    for (int off = 32; off > 0; off >>= 1) acc += __shfl_down(acc, off);
    __shared__ double wsum[4];
    if (lane == 0) wsum[wid] = acc;
    __syncthreads();
    if (threadIdx.x == 0)
        blk_sum[blockIdx.x] = wsum[0] + wsum[1] + wsum[2] + wsum[3];

    // Block top-5: 5 rounds of (wave shfl argmax on keys -> cross-wave -> pop).
    __shared__ u64 bsk[4];
    for (int r = 0; r < 5; ++r) {
        const u64 ck = k0;
        u64 wk = ck;
        for (int off = 1; off < 64; off <<= 1) {
            u64 ok = __shfl_xor(wk, off);
            if (ok > wk) wk = ok;
        }
        if (lane == 0) bsk[wid] = wk;
        __syncthreads();
        u64 gk = bsk[0];
        if (bsk[1] > gk) gk = bsk[1];
        if (bsk[2] > gk) gk = bsk[2];
        if (bsk[3] > gk) gk = bsk[3];
        if (threadIdx.x == 0) cand_k[blockIdx.x * 5 + r] = gk;
        if (gk == ck) {  // keys unique -> exactly one owner pops
            k0 = k1; k1 = k2; k2 = k3; k3 = k4; k4 = 0;
        }
        __syncthreads();  // WAR: bsk reused next round
    }
}

__global__ __launch_bounds__(TPB) void reward_pass2(
        const double* __restrict__ blk_sum,
        const u64* __restrict__ cand_k,
        const float* __restrict__ ret,
        float* __restrict__ out,
        int nb, int n) {
    const int lane = threadIdx.x & 63;
    const int wid  = threadIdx.x >> 6;

    // Sum of partials.
    double acc = 0.0;
    for (int i = threadIdx.x; i < nb; i += TPB) acc += blk_sum[i];
    for (int off = 32; off > 0; off >>= 1) acc += __shfl_down(acc, off);
    __shared__ double wsum[4];
    if (lane == 0) wsum[wid] = acc;
    __syncthreads();

    // Per-thread top-5 over candidate keys (branchless ladder).
    u64 k0 = 0, k1 = 0, k2 = 0, k3 = 0, k4 = 0;
    const int nc = nb * 5;
    for (int i = threadIdx.x; i < nc; i += TPB) {
        const u64 _key = cand_k[i];
        const bool c0 = _key > k0;
        const bool c1 = _key > k1;
        const bool c2 = _key > k2;
        const bool c3 = _key > k3;
        const bool c4 = _key > k4;
        k4 = c3 ? k3 : (c4 ? _key : k4);
        k3 = c2 ? k2 : (c3 ? _key : k3);
        k2 = c1 ? k1 : (c2 ? _key : k2);
        k1 = c0 ? k0 : (c1 ? _key : k1);
        k0 = c0 ? _key : k0;
    }

    // 5 rounds block argmax + pop -> global top-5 indices.
    __shared__ u64 bsk[4];
    __shared__ int winner[5];
    for (int r = 0; r < 5; ++r) {
        const u64 ck = k0;
        u64 wk = ck;
        for (int off = 1; off < 64; off <<= 1) {
            u64 ok = __shfl_xor(wk, off);
            if (ok > wk) wk = ok;
        }
        if (lane == 0) bsk[wid] = wk;
        __syncthreads();
        u64 gk = bsk[0];
        if (bsk[1] > gk) gk = bsk[1];
        if (bsk[2] > gk) gk = bsk[2];
        if (bsk[3] > gk) gk = bsk[3];
        if (threadIdx.x == 0) winner[r] = (int)(~(u32)gk);
        if (gk == ck) {
            k0 = k1; k1 = k2; k2 = k3; k3 = k4; k4 = 0;
        }
        __syncthreads();
    }

    if (threadIdx.x == 0) {
        double corr = 0.0;
        for (int r = 0; r < 5; ++r) {
            int idx = winner[r];
            float rr = ret[idx];
            float a = fabsf(rr);
            float strict, mid;
            if (rr < 0.0f)       { strict = 0.005f * a;  mid = 0.0025f * a; }
            else if (rr >= 2.0f) { strict = -0.02f * rr; mid = -0.01f * rr; }
            else if (rr > 0.0f)  { strict = -0.01f * rr; mid = -0.005f * rr; }
            else                 { strict = 0.0f;        mid = 0.0f; }
            float rest = (rr >= 2.0f) ? 0.0015f * rr : 0.0f;
            float bucket = (r < 3) ? strict : mid;  // ranks 1..3 strict, 4..5 mid
            corr += (double)(bucket - rest);
        }
        out[0] = (float)((wsum[0] + wsum[1] + wsum[2] + wsum[3] + corr) / (double)n);
    }
}

extern "C" void kernel_launch(void* const* d_in, const int* in_sizes, int n_in,
                              void* d_out, int out_size, void* d_ws, size_t ws_size,
                              hipStream_t stream) {
    const float* pred = (const float*)d_in[0];
    const float* tru  = (const float*)d_in[1];
    const float* ret  = (const float*)d_in[2];
    float* out = (float*)d_out;
    const int n = in_sizes[0];

    int nb = 2048;
    // Per-block scratch: 8B sum + 5*8B candidate keys = 48B. Fit within ws_size.
    while (nb > 64 && (size_t)nb * 48 > ws_size) nb >>= 1;

    double* blk_sum = (double*)d_ws;
    u64*    cand_k  = (u64*)(blk_sum + nb);

    reward_pass1<<<nb, TPB, 0, stream>>>(pred, tru, ret, blk_sum, cand_k, n);
    reward_pass2<<<1, TPB, 0, stream>>>(blk_sum, cand_k, ret, out, nb, n);
}

// Round 7
// 48.959 us; speedup vs baseline: 1.2856x; 1.2008x over previous
//
#include <hip/hip_runtime.h>
#include <math.h>

#define TPB 256

typedef unsigned long long u64;
typedef unsigned int u32;
// Clang ext vector for __builtin_nontemporal_load (emits global_load_dwordx4 nt).
typedef float f4 __attribute__((ext_vector_type(4)));

// Packed sort key: strictly increasing in value; ties -> smaller index wins.
// u64 compare (>) == better(v1,i1,v2,i2) from jnp.argsort(-scores) stability.
__device__ __forceinline__ u64 mkkey(float v, int idx) {
    u32 u = __float_as_uint(v);
    u ^= (u32)(((int)u) >> 31) | 0x80000000u;   // monotone float->uint map
    return ((u64)u << 32) | (u32)(~idx);
}

// Branchless top-5 update on named u64 scalars (k0 >= k1 >= ... >= k4).
#define UPD(v, idx)                                             \
    {                                                           \
        const u64 _key = mkkey((v), (idx));                     \
        const bool c0 = _key > k0;                              \
        const bool c1 = _key > k1;                              \
        const bool c2 = _key > k2;                              \
        const bool c3 = _key > k3;                              \
        const bool c4 = _key > k4;                              \
        k4 = c3 ? k3 : (c4 ? _key : k4);                        \
        k3 = c2 ? k2 : (c3 ? _key : k3);                        \
        k2 = c1 ? k1 : (c2 ? _key : k2);                        \
        k1 = c0 ? k0 : (c1 ? _key : k1);                        \
        k0 = c0 ? _key : k0;                                    \
    }

// Process one quad already in registers. Fully branchless.
#define PROC(p, t, r, qi)                                                   \
    {                                                                       \
        float d;                                                            \
        d = p.x - t.x; accb = fmaf(d, d, accb);                             \
        d = p.y - t.y; accb = fmaf(d, d, accb);                             \
        d = p.z - t.z; accb = fmaf(d, d, accb);                             \
        d = p.w - t.w; accb = fmaf(d, d, accb);                             \
        accr += (r.x >= 2.0f ? r.x : 0.0f) + (r.y >= 2.0f ? r.y : 0.0f)     \
              + (r.z >= 2.0f ? r.z : 0.0f) + (r.w >= 2.0f ? r.w : 0.0f);    \
        const int _b = (qi) * 4;                                            \
        UPD(p.x, _b);                                                       \
        UPD(p.y, _b + 1);                                                   \
        UPD(p.z, _b + 2);                                                   \
        UPD(p.w, _b + 3);                                                   \
    }

#define NTLOAD(ptr) __builtin_nontemporal_load(ptr)

__global__ __launch_bounds__(TPB) void reward_pass1(
        const float* __restrict__ pred,
        const float* __restrict__ tru,
        const float* __restrict__ ret,
        double* __restrict__ blk_sum,
        u64* __restrict__ cand_k,
        int n) {
    const int n4 = n >> 2;
    const f4* __restrict__ pred4 = (const f4*)pred;
    const f4* __restrict__ tru4  = (const f4*)tru;
    const f4* __restrict__ ret4  = (const f4*)ret;

    float accb = 0.0f;   // sum of (pred-true)^2
    float accr = 0.0f;   // sum of ret where ret >= 2 (rest_adj = 0.0015 * that)
    u64 k0 = 0, k1 = 0, k2 = 0, k3 = 0, k4 = 0;  // real keys are always > 0

    // Slab indexing (R7 change): block b streams the contiguous quad range
    // [b*qpb, (b+1)*qpb) of each array — contiguous 32KB/array per slab pass
    // for DRAM row/channel locality, instead of interleaving 1KB wave-chunks
    // across the whole 67MB. nt loads kept (the R6 win: 72 -> 44 us).
    const int qpb = n4 / gridDim.x;            // quads per block (floor)
    const int base = blockIdx.x * qpb;
    int j = threadIdx.x;
    for (; j + 3 * TPB < qpb; j += 4 * TPB) {
        const int ia = base + j;
        const int ib = ia + TPB;
        const int ic = ib + TPB;
        const int id = ic + TPB;
        f4 pa = NTLOAD(pred4 + ia), pb = NTLOAD(pred4 + ib),
           pc = NTLOAD(pred4 + ic), pd = NTLOAD(pred4 + id);
        f4 ta = NTLOAD(tru4 + ia),  tb = NTLOAD(tru4 + ib),
           tc = NTLOAD(tru4 + ic),  td = NTLOAD(tru4 + id);
        f4 ra = NTLOAD(ret4 + ia),  rb = NTLOAD(ret4 + ib),
           rc = NTLOAD(ret4 + ic),  rd = NTLOAD(ret4 + id);
        PROC(pa, ta, ra, ia)
        PROC(pb, tb, rb, ib)
        PROC(pc, tc, rc, ic)
        PROC(pd, td, rd, id)
    }
    for (; j < qpb; j += TPB) {
        const int iq = base + j;
        const f4 p = NTLOAD(pred4 + iq);
        const f4 t = NTLOAD(tru4 + iq);
        const f4 r = NTLOAD(ret4 + iq);
        PROC(p, t, r, iq)
    }

    // Remainder quads (n4 not divisible by gridDim): rem < gridDim <= total
    // threads, so one conditional quad per global thread covers it.
    {
        const int rem_base = qpb * gridDim.x;
        const int gq = rem_base + blockIdx.x * TPB + threadIdx.x;
        if (gq < n4) {
            const f4 p = NTLOAD(pred4 + gq);
            const f4 t = NTLOAD(tru4 + gq);
            const f4 r = NTLOAD(ret4 + gq);
            PROC(p, t, r, gq)
        }
    }

    // Scalar tail (n not multiple of 4), handled by one thread.
    if (blockIdx.x == 0 && threadIdx.x == 0) {
        for (int kk = n4 * 4; kk < n; ++kk) {
            float d = pred[kk] - tru[kk];
            accb = fmaf(d, d, accb);
            float rr = ret[kk];
            accr += (rr >= 2.0f ? rr : 0.0f);
            UPD(pred[kk], kk);
        }
    }

    const int lane = threadIdx.x & 63;
    const int wid  = threadIdx.x >> 6;

    // Block sum: wave shuffle reduce (double), then 4 wave partials via LDS.
    double acc = (double)accb + 0.0015 * (double)accr;
    for (int off = 32; off > 0; off >>= 1) acc += __shfl_down(acc, off);
    __shared__ double wsum[4];
    if (lane == 0) wsum[wid] = acc;
    __syncthreads();
    if (threadIdx.x == 0)
        blk_sum[blockIdx.x] = wsum[0] + wsum[1] + wsum[2] + wsum[3];

    // Block top-5: 5 rounds of (wave shfl argmax on keys -> cross-wave -> pop).
    __shared__ u64 bsk[4];
    for (int r = 0; r < 5; ++r) {
        const u64 ck = k0;
        u64 wk = ck;
        for (int off = 1; off < 64; off <<= 1) {
            u64 ok = __shfl_xor(wk, off);
            if (ok > wk) wk = ok;
        }
        if (lane == 0) bsk[wid] = wk;
        __syncthreads();
        u64 gk = bsk[0];
        if (bsk[1] > gk) gk = bsk[1];
        if (bsk[2] > gk) gk = bsk[2];
        if (bsk[3] > gk) gk = bsk[3];
        if (threadIdx.x == 0) cand_k[blockIdx.x * 5 + r] = gk;
        if (gk == ck) {  // keys unique -> exactly one owner pops
            k0 = k1; k1 = k2; k2 = k3; k3 = k4; k4 = 0;
        }
        __syncthreads();  // WAR: bsk reused next round
    }
}

// Pass 2 (R7 rewrite): 1024 threads (16 waves) + 16B vector reads. The R6
// version (256 thr, 8B/lane serial strides) was ~10-14 us of pure latency.
#define TPB2 1024
__global__ __launch_bounds__(TPB2) void reward_pass2(
        const double* __restrict__ blk_sum,
        const u64* __restrict__ cand_k,
        const float* __restrict__ ret,
        float* __restrict__ out,
        int nb, int n) {
    const int lane = threadIdx.x & 63;
    const int wid  = threadIdx.x >> 6;   // 0..15

    // Sum of partials (double2 = 16B loads; nb is a power of two >= 64).
    double acc = 0.0;
    const double2* __restrict__ bs2 = (const double2*)blk_sum;
    const int nb2 = nb >> 1;
    for (int i = threadIdx.x; i < nb2; i += TPB2) {
        double2 v = bs2[i];
        acc += v.x + v.y;
    }
    for (int off = 32; off > 0; off >>= 1) acc += __shfl_down(acc, off);
    __shared__ double wsum[16];
    if (lane == 0) wsum[wid] = acc;
    __syncthreads();

    // Per-thread top-5 over candidate keys, 2 keys per 16B load.
    u64 k0 = 0, k1 = 0, k2 = 0, k3 = 0, k4 = 0;
    const ulonglong2* __restrict__ ck2 = (const ulonglong2*)cand_k;
    const int npairs = (nb * 5) >> 1;   // nb even -> exact
    for (int i = threadIdx.x; i < npairs; i += TPB2) {
        const ulonglong2 kp = ck2[i];
        {
            const u64 _key = kp.x;
            const bool c0 = _key > k0; const bool c1 = _key > k1;
            const bool c2 = _key > k2; const bool c3 = _key > k3;
            const bool c4 = _key > k4;
            k4 = c3 ? k3 : (c4 ? _key : k4);
            k3 = c2 ? k2 : (c3 ? _key : k3);
            k2 = c1 ? k1 : (c2 ? _key : k2);
            k1 = c0 ? k0 : (c1 ? _key : k1);
            k0 = c0 ? _key : k0;
        }
        {
            const u64 _key = kp.y;
            const bool c0 = _key > k0; const bool c1 = _key > k1;
            const bool c2 = _key > k2; const bool c3 = _key > k3;
            const bool c4 = _key > k4;
            k4 = c3 ? k3 : (c4 ? _key : k4);
            k3 = c2 ? k2 : (c3 ? _key : k3);
            k2 = c1 ? k1 : (c2 ? _key : k2);
            k1 = c0 ? k0 : (c1 ? _key : k1);
            k0 = c0 ? _key : k0;
        }
    }

    // 5 rounds block argmax + pop -> global top-5 indices.
    __shared__ u64 bsk[16];
    __shared__ int winner[5];
    for (int r = 0; r < 5; ++r) {
        const u64 ck = k0;
        u64 wk = ck;
        for (int off = 1; off < 64; off <<= 1) {
            u64 ok = __shfl_xor(wk, off);
            if (ok > wk) wk = ok;
        }
        if (lane == 0) bsk[wid] = wk;
        __syncthreads();
        u64 gk = bsk[0];
#pragma unroll
        for (int w = 1; w < 16; ++w)
            if (bsk[w] > gk) gk = bsk[w];
        if (threadIdx.x == 0) winner[r] = (int)(~(u32)gk);
        if (gk == ck) {
            k0 = k1; k1 = k2; k2 = k3; k3 = k4; k4 = 0;
        }
        __syncthreads();
    }

    if (threadIdx.x == 0) {
        double tot = 0.0;
#pragma unroll
        for (int w = 0; w < 16; ++w) tot += wsum[w];
        double corr = 0.0;
        for (int r = 0; r < 5; ++r) {
            int idx = winner[r];
            float rr = ret[idx];
            float a = fabsf(rr);
            float strict, mid;
            if (rr < 0.0f)       { strict = 0.005f * a;  mid = 0.0025f * a; }
            else if (rr >= 2.0f) { strict = -0.02f * rr; mid = -0.01f * rr; }
            else if (rr > 0.0f)  { strict = -0.01f * rr; mid = -0.005f * rr; }
            else                 { strict = 0.0f;        mid = 0.0f; }
            float rest = (rr >= 2.0f) ? 0.0015f * rr : 0.0f;
            float bucket = (r < 3) ? strict : mid;  // ranks 1..3 strict, 4..5 mid
            corr += (double)(bucket - rest);
        }
        out[0] = (float)((tot + corr) / (double)n);
    }
}

extern "C" void kernel_launch(void* const* d_in, const int* in_sizes, int n_in,
                              void* d_out, int out_size, void* d_ws, size_t ws_size,
                              hipStream_t stream) {
    const float* pred = (const float*)d_in[0];
    const float* tru  = (const float*)d_in[1];
    const float* ret  = (const float*)d_in[2];
    float* out = (float*)d_out;
    const int n = in_sizes[0];

    int nb = 2048;
    // Per-block scratch: 8B sum + 5*8B candidate keys = 48B. Fit within ws_size.
    while (nb > 64 && (size_t)nb * 48 > ws_size) nb >>= 1;

    double* blk_sum = (double*)d_ws;
    u64*    cand_k  = (u64*)(blk_sum + nb);

    reward_pass1<<<nb, TPB, 0, stream>>>(pred, tru, ret, blk_sum, cand_k, n);
    reward_pass2<<<1, TPB2, 0, stream>>>(blk_sum, cand_k, ret, out, nb, n);
}